// Round 9
// baseline (121.187 us; speedup 1.0000x reference)
//
#include <hip/hip_runtime.h>
#include <hip/hip_bf16.h>
#include <climits>

#define BATCH   2
#define NPTS    16384   // N
#define NQ      4096    // P
#define CFEAT   64
#define NS      32      // nsample
#define R2      0.01f   // radius^2
#define COUT    (3 + CFEAT)   // 67
#define GDIM    10      // grid cells per axis (cell size = radius)
#define NCELL   (GDIM * GDIM * GDIM)
#define NWORDS  (NPTS / 32)   // 512 words per bitmask

// ---- ws layout (bytes) ----
#define FEATT_BYTES ((size_t)BATCH * NPTS * CFEAT * sizeof(unsigned short))
#define PXYZJ_BYTES ((size_t)BATCH * NPTS * sizeof(float4))
#define OFF_CNT    0
#define OFF_FILL   (2 * NCELL)
#define OFF_CSTART (4 * NCELL)
#define GRID_INTS  (4 * NCELL + 2 * (NCELL + 1))

__device__ __forceinline__ int cell_of(float x, float y, float z) {
    int cx = (int)(x * GDIM); cx = cx < 0 ? 0 : (cx > GDIM - 1 ? GDIM - 1 : cx);
    int cy = (int)(y * GDIM); cy = cy < 0 ? 0 : (cy > GDIM - 1 ? GDIM - 1 : cy);
    int cz = (int)(z * GDIM); cz = cz < 0 ? 0 : (cz > GDIM - 1 ? GDIM - 1 : cz);
    return (cz * GDIM + cy) * GDIM + cx;   // x fastest -> contiguous x-runs
}

__device__ __forceinline__ unsigned short f2bf(float f) {
    unsigned b = __float_as_uint(f);
    return (unsigned short)((b + 0x7FFFu + ((b >> 16) & 1u)) >> 16);   // RNE
}

// ------- fused: transpose->bf16 (blocks 0..511, float4 loads)
//         + count (blocks 512..639) ----
__global__ __launch_bounds__(256) void prep1_kernel(
    const float* __restrict__ feat, unsigned short* __restrict__ featT16,
    const float* __restrict__ xyz, int* __restrict__ cnt)
{
    __shared__ float tile[64][65];
    if (blockIdx.x < 512) {
        const int b    = blockIdx.x >> 8;
        const int n0   = (blockIdx.x & 255) * 64;
        const int lane = threadIdx.x & 63;
        const int grp  = threadIdx.x >> 6;           // 0..3
        const float* fb = feat + (size_t)b * CFEAT * NPTS;
        const int col4 = (lane & 15) << 2;           // 0,4,..,60
        #pragma unroll
        for (int k = 0; k < 4; ++k) {
            const int c = grp * 16 + k * 4 + (lane >> 4);
            const float4 v = *(const float4*)&fb[(size_t)c * NPTS + n0 + col4];
            tile[c][col4 + 0] = v.x;
            tile[c][col4 + 1] = v.y;
            tile[c][col4 + 2] = v.z;
            tile[c][col4 + 3] = v.w;
        }
        __syncthreads();
        unsigned short* db = featT16 + ((size_t)b * NPTS + n0) * CFEAT;
        #pragma unroll
        for (int k = 0; k < 8; ++k) {
            const int e   = threadIdx.x + 256 * k;
            const int row = e >> 5;           // 0..63 (point within tile)
            const int c2  = e & 31;           // channel pair
            ushort2 v;
            v.x = f2bf(tile[2 * c2][row]);
            v.y = f2bf(tile[2 * c2 + 1][row]);
            ((ushort2*)(db + (size_t)row * CFEAT))[c2] = v;
        }
    } else {
        const int g = (blockIdx.x - 512) * 256 + threadIdx.x;   // 0..B*N-1
        const int b = g >> 14;
        const int c = cell_of(xyz[g*3], xyz[g*3+1], xyz[g*3+2]);
        atomicAdd(&cnt[b * NCELL + c], 1);
    }
}

// ---------------- scan (redundant per block, in LDS) + scatter ----------------
__global__ __launch_bounds__(256) void prep2_kernel(
    const float* __restrict__ xyz, const int* __restrict__ cnt,
    int* __restrict__ fill, int* __restrict__ cstart,
    float4* __restrict__ pxyzj)
{
    __shared__ int scs[2 * NCELL];       // exclusive starts, both batches
    const int tid  = threadIdx.x;
    const int lane = tid & 63;

    if (tid < 128) {
        const int b = tid >> 6;
        int c16[16];
        int tot = 0;
        #pragma unroll
        for (int k = 0; k < 16; ++k) {
            const int i = lane * 16 + k;
            c16[k] = (i < NCELL) ? cnt[b * NCELL + i] : 0;
            tot += c16[k];
        }
        int ex = tot;
        #pragma unroll
        for (int off = 1; off < 64; off <<= 1) {
            const int u = __shfl_up(ex, off);
            if (lane >= off) ex += u;
        }
        ex -= tot;
        int run = ex;
        #pragma unroll
        for (int k = 0; k < 16; ++k) {
            const int i = lane * 16 + k;
            if (i < NCELL) scs[b * NCELL + i] = run;
            run += c16[k];
        }
    }
    __syncthreads();

    if (blockIdx.x == 0) {
        for (int i = tid; i < 2 * (NCELL + 1); i += 256) {
            const int b  = i / (NCELL + 1);
            const int ci = i - b * (NCELL + 1);
            cstart[i] = (ci == NCELL) ? NPTS : scs[b * NCELL + ci];
        }
    }

    const int g = blockIdx.x * 256 + tid;
    const int b = g >> 14;
    const int j = g & (NPTS - 1);
    const float x = xyz[g*3], y = xyz[g*3+1], z = xyz[g*3+2];
    const int c = cell_of(x, y, z);
    const int pos = atomicAdd(&fill[b * NCELL + c], 1);
    pxyzj[b * NPTS + scs[b * NCELL + c] + pos] =
        make_float4(x, y, z, __int_as_float(j));
}

// ---------------- fused main: 4 SEQUENTIAL QUERIES PER WAVE -----------------
// R9: R8 (XCD swizzle, confirmed +4us) + shrunken in-flight write window:
// grid 512 blocks (64/XCD co-resident), each wave owns 4 consecutive queries
// processed sequentially -> concurrent write window per XCD ~2.2MB < 4MB L2,
// so L2 aggregates full contiguous runs before writeback.
__global__ __launch_bounds__(256) void qg_fused(
    const float* __restrict__ xyz,               // (B, N, 3)
    const float* __restrict__ new_xyz,           // (B, P, 3)
    const int* __restrict__ cstart,              // (B, NCELL+1)
    const float4* __restrict__ pxyzj,            // (B, N) sorted {x,y,z,j}
    const unsigned short* __restrict__ featT16,  // (B, N, C) bf16
    float* __restrict__ out)                     // (B, 67, P, S)
{
    const int tid  = threadIdx.x;       // 0..255
    const int wave = tid >> 6;          // 0..3
    const int lane = tid & 63;
    // XCD swizzle over 512 blocks: XCD x owns blocks swz in [x*64,(x+1)*64)
    // -> contiguous queries [x*1024, (x+1)*1024).
    const int swz   = ((blockIdx.x & 7) << 6) + (blockIdx.x >> 3);
    const int qbase = (swz << 4) + (wave << 2);  // wave: queries qbase..qbase+3

    __shared__ __align__(16) unsigned char smem[4 * 2176];
    unsigned char* wbase = smem + wave * 2176;
    unsigned int* hmask  = (unsigned int*)wbase;        // 512 words
    int* idx_s           = (int*)(wbase + 2048);        // 32 ints

    #pragma unroll 1
    for (int it = 0; it < 4; ++it) {
        const int q = qbase + it;
        const int b = q >> 12;
        const int p = q & (NQ - 1);

        // zero own bitmask: 64 lanes x 2 uint4 = 2KB
        {
            uint4 z; z.x = 0; z.y = 0; z.z = 0; z.w = 0;
            ((uint4*)hmask)[lane * 2]     = z;
            ((uint4*)hmask)[lane * 2 + 1] = z;
        }

        const float qx = new_xyz[q * 3 + 0];
        const float qy = new_xyz[q * 3 + 1];
        const float qz = new_xyz[q * 3 + 2];
        const float* xb = xyz + (size_t)b * NPTS * 3;
        const int* cs = cstart + b * (NCELL + 1);
        const float4* pb = pxyzj + (size_t)b * NPTS;

        int qcx = (int)(qx * GDIM); qcx = qcx < 0 ? 0 : (qcx > GDIM-1 ? GDIM-1 : qcx);
        int qcy = (int)(qy * GDIM); qcy = qcy < 0 ? 0 : (qcy > GDIM-1 ? GDIM-1 : qcy);
        int qcz = (int)(qz * GDIM); qcz = qcz < 0 ? 0 : (qcz > GDIM-1 ? GDIM-1 : qcz);
        const int x0 = qcx > 0 ? qcx - 1 : 0;
        const int x1 = qcx < GDIM-1 ? qcx + 1 : GDIM-1;
        const int y0 = qcy > 0 ? qcy - 1 : 0;
        const int y1 = qcy < GDIM-1 ? qcy + 1 : GDIM-1;
        const int z0 = qcz > 0 ? qcz - 1 : 0;
        const int z1 = qcz < GDIM-1 ? qcz + 1 : GDIM-1;
        const int ny  = y1 - y0 + 1;                 // 2 or 3
        const int nyz = ny * (z1 - z0 + 1);          // up to 9

        int sv = 0, ev = 0;
        if (lane < nyz) {
            const int gzi = (ny == 3) ? ((lane * 86) >> 8) : (lane >> 1);
            const int gyi = lane - gzi * ny;
            const int crow = ((z0 + gzi) * GDIM + (y0 + gyi)) * GDIM;
            sv = cs[crow + x0];
            ev = cs[crow + x1 + 1];
        }
        __builtin_amdgcn_wave_barrier();    // bitmask zero ordered before atomics

        for (int r = 0; r < nyz; ++r) {
            const int s = __shfl(sv, r);
            const int e = __shfl(ev, r);
            for (int pos = s; pos < e; pos += 64) {
                const int i = pos + lane;
                const bool inr = i < e;
                const float4 pt = pb[inr ? i : 0];   // coalesced dwordx4
                const float dx = pt.x - qx;
                const float dy = pt.y - qy;
                const float dz = pt.z - qz;
                if (inr && (dx*dx + dy*dy + dz*dz < R2)) {
                    const int j = __float_as_int(pt.w);
                    atomicOr(&hmask[j >> 5], 1u << (j & 31));
                }
            }
        }
        __builtin_amdgcn_wave_barrier();    // all hits landed (same-wave DS order)

        // ---- extraction ----
        int K;
        {
            unsigned int w[8];
            const uint4 a = ((const uint4*)hmask)[lane * 2];
            const uint4 c = ((const uint4*)hmask)[lane * 2 + 1];
            w[0] = a.x; w[1] = a.y; w[2] = a.z; w[3] = a.w;
            w[4] = c.x; w[5] = c.y; w[6] = c.z; w[7] = c.w;

            int cnt8 = 0;
            #pragma unroll
            for (int k = 0; k < 8; ++k) cnt8 += __popc(w[k]);

            int pfx = cnt8;
            #pragma unroll
            for (int off = 1; off < 64; off <<= 1) {
                const int u = __shfl_up(pfx, off);
                if (lane >= off) pfx += u;
            }
            K = __shfl(pfx, 63);
            pfx -= cnt8;

            if (pfx < NS && cnt8 > 0) {
                int r = pfx;
                #pragma unroll
                for (int k = 0; k < 8; ++k) {
                    unsigned int m = w[k];
                    while (m && r < NS) {
                        const int bit = __builtin_ctz(m);
                        idx_s[r] = lane * 256 + k * 32 + bit;
                        m &= m - 1;
                        ++r;
                    }
                }
            }
            __builtin_amdgcn_wave_barrier();
            if (lane < NS && lane >= K) {
                idx_s[lane] = (K > 0) ? idx_s[0] : 0;
            }
            __builtin_amdgcn_wave_barrier();
        }

        // ---- gather + direct write (no LDS tile) ----
        const int sm = lane >> 1;           // sample 0..31
        const int h  = lane & 1;            // half-row: 32 channels each
        const int jrow = idx_s[sm];
        const uint4* bptr = (const uint4*)(featT16 +
            ((size_t)b * NPTS + jrow) * CFEAT + (h << 5));
        const uint4 ga = bptr[0];
        const uint4 gb = bptr[1];
        const uint4 gc = bptr[2];
        const uint4 gd = bptr[3];

        const size_t cstride = (size_t)NQ * NS;
        const size_t out_q   = ((size_t)b * COUT * NQ + (size_t)p) * NS;

        if (lane < NS) {
            const int j = idx_s[lane];
            out[out_q + 0*cstride + lane] = xb[j*3+0] - qx;
            out[out_q + 1*cstride + lane] = xb[j*3+1] - qy;
            out[out_q + 2*cstride + lane] = xb[j*3+2] - qz;
        }

        // lane (sm,h) holds 32 channels (16 dwords) of sample sm.
        float* fob = out + out_q + (size_t)(3 + (h << 5)) * cstride + sm;
        const unsigned comps[16] = {ga.x, ga.y, ga.z, ga.w,
                                    gb.x, gb.y, gb.z, gb.w,
                                    gc.x, gc.y, gc.z, gc.w,
                                    gd.x, gd.y, gd.z, gd.w};
        #pragma unroll
        for (int kk = 0; kk < 16; ++kk) {
            const unsigned u = comps[kk];
            fob[(size_t)(2*kk)     * cstride] = __uint_as_float(u << 16);
            fob[(size_t)(2*kk + 1) * cstride] = __uint_as_float(u & 0xFFFF0000u);
        }
        __builtin_amdgcn_wave_barrier();    // keep iterations cleanly ordered
    }
}

// ---------------- fallback: linear-scan kernel (fp32 exact) ----------------
__global__ __launch_bounds__(256) void qg_linear(
    const float* __restrict__ xyz, const float* __restrict__ new_xyz,
    const float* __restrict__ feat, float* __restrict__ out)
{
    const int wave = threadIdx.x >> 6;
    const int lane = threadIdx.x & 63;
    const int bp   = blockIdx.x * 4 + wave;
    const int b    = bp >> 12;
    const int p    = bp & (NQ - 1);
    __shared__ int idx_s[4][NS];
    const float qx = new_xyz[bp*3+0], qy = new_xyz[bp*3+1], qz = new_xyz[bp*3+2];
    const float* xb = xyz + (size_t)b * NPTS * 3;
    int cnt = 0;
    const unsigned long long below = (1ull << lane) - 1ull;
    for (int base = 0; base < NPTS; base += 64) {
        const int j = base + lane;
        const float dx = xb[j*3+0]-qx, dy = xb[j*3+1]-qy, dz = xb[j*3+2]-qz;
        const bool hit = dx*dx+dy*dy+dz*dz < R2;
        const unsigned long long m = __ballot(hit);
        if (hit) {
            const int slot = cnt + __popcll(m & below);
            if (slot < NS) idx_s[wave][slot] = j;
        }
        cnt += __popcll(m);
        if (cnt >= NS) break;
    }
    __builtin_amdgcn_wave_barrier();
    if (cnt < NS) {
        const int first = (cnt > 0) ? idx_s[wave][0] : 0;
        if (lane >= cnt && lane < NS) idx_s[wave][lane] = first;
    }
    __builtin_amdgcn_wave_barrier();
    const size_t cstride = (size_t)NQ * NS;
    const size_t out_q = ((size_t)b * COUT * NQ + (size_t)p) * NS;
    if (lane < NS) {
        const int j = idx_s[wave][lane];
        out[out_q + 0*cstride + lane] = xb[j*3+0] - qx;
        out[out_q + 1*cstride + lane] = xb[j*3+1] - qy;
        out[out_q + 2*cstride + lane] = xb[j*3+2] - qz;
    }
    const float* fb = feat + (size_t)b * CFEAT * NPTS;
    const int s = lane & 31, half = lane >> 5;
    const int j = idx_s[wave][s];
    #pragma unroll 8
    for (int c = half; c < CFEAT; c += 2)
        out[out_q + (size_t)(3 + c) * cstride + s] = fb[(size_t)c * NPTS + j];
}

extern "C" void kernel_launch(void* const* d_in, const int* in_sizes, int n_in,
                              void* d_out, int out_size, void* d_ws, size_t ws_size,
                              hipStream_t stream) {
    const float* xyz     = (const float*)d_in[0];  // (2,16384,3)
    const float* new_xyz = (const float*)d_in[1];  // (2,4096,3)
    const float* feat    = (const float*)d_in[2];  // (2,64,16384)
    float* out = (float*)d_out;                    // (2,67,4096,32)

    const size_t need_full = FEATT_BYTES + PXYZJ_BYTES + (size_t)GRID_INTS * sizeof(int);

    if (ws_size >= need_full) {
        unsigned short* featT16 = (unsigned short*)d_ws;
        float4* pxyzj = (float4*)((char*)d_ws + FEATT_BYTES);
        int* gi = (int*)((char*)d_ws + FEATT_BYTES + PXYZJ_BYTES);
        int* cnt    = gi + OFF_CNT;
        int* fill   = gi + OFF_FILL;
        int* cstart = gi + OFF_CSTART;

        hipMemsetAsync(cnt, 0, 4 * NCELL * sizeof(int), stream);  // cnt + fill
        prep1_kernel<<<512 + (BATCH * NPTS) / 256, 256, 0, stream>>>(feat, featT16, xyz, cnt);
        prep2_kernel<<<(BATCH * NPTS) / 256, 256, 0, stream>>>(xyz, cnt, fill, cstart, pxyzj);
        qg_fused<<<512, 256, 0, stream>>>(
            xyz, new_xyz, cstart, pxyzj, featT16, out);
    } else {
        qg_linear<<<(BATCH * NQ) / 4, 256, 0, stream>>>(xyz, new_xyz, feat, out);
    }
}

// Round 10
// 109.965 us; speedup vs baseline: 1.1020x; 1.1020x over previous
//
#include <hip/hip_runtime.h>
#include <hip/hip_bf16.h>
#include <climits>

#define BATCH   2
#define NPTS    16384   // N
#define NQ      4096    // P
#define CFEAT   64
#define NS      32      // nsample
#define R2      0.01f   // radius^2
#define COUT    (3 + CFEAT)   // 67
#define GDIM    10      // grid cells per axis (cell size = radius)
#define NCELL   (GDIM * GDIM * GDIM)
#define NWORDS  (NPTS / 32)   // 512 words per bitmask

// ---- ws layout (bytes) ----
#define FEATT_BYTES ((size_t)BATCH * NPTS * CFEAT * sizeof(unsigned short))
#define PXYZJ_BYTES ((size_t)BATCH * NPTS * sizeof(float4))
#define OFF_CNT    0
#define OFF_FILL   (2 * NCELL)
#define OFF_CSTART (4 * NCELL)
#define GRID_INTS  (4 * NCELL + 2 * (NCELL + 1))

__device__ __forceinline__ int cell_of(float x, float y, float z) {
    int cx = (int)(x * GDIM); cx = cx < 0 ? 0 : (cx > GDIM - 1 ? GDIM - 1 : cx);
    int cy = (int)(y * GDIM); cy = cy < 0 ? 0 : (cy > GDIM - 1 ? GDIM - 1 : cy);
    int cz = (int)(z * GDIM); cz = cz < 0 ? 0 : (cz > GDIM - 1 ? GDIM - 1 : cz);
    return (cz * GDIM + cy) * GDIM + cx;   // x fastest -> contiguous x-runs
}

__device__ __forceinline__ unsigned short f2bf(float f) {
    unsigned b = __float_as_uint(f);
    return (unsigned short)((b + 0x7FFFu + ((b >> 16) & 1u)) >> 16);   // RNE
}

// ------- fused: transpose->bf16 (blocks 0..511, float4 loads)
//         + count (blocks 512..639) ----
__global__ __launch_bounds__(256) void prep1_kernel(
    const float* __restrict__ feat, unsigned short* __restrict__ featT16,
    const float* __restrict__ xyz, int* __restrict__ cnt)
{
    __shared__ float tile[64][65];
    if (blockIdx.x < 512) {
        const int b    = blockIdx.x >> 8;
        const int n0   = (blockIdx.x & 255) * 64;
        const int lane = threadIdx.x & 63;
        const int grp  = threadIdx.x >> 6;           // 0..3
        const float* fb = feat + (size_t)b * CFEAT * NPTS;
        const int col4 = (lane & 15) << 2;           // 0,4,..,60
        #pragma unroll
        for (int k = 0; k < 4; ++k) {
            const int c = grp * 16 + k * 4 + (lane >> 4);
            const float4 v = *(const float4*)&fb[(size_t)c * NPTS + n0 + col4];
            tile[c][col4 + 0] = v.x;
            tile[c][col4 + 1] = v.y;
            tile[c][col4 + 2] = v.z;
            tile[c][col4 + 3] = v.w;
        }
        __syncthreads();
        unsigned short* db = featT16 + ((size_t)b * NPTS + n0) * CFEAT;
        #pragma unroll
        for (int k = 0; k < 8; ++k) {
            const int e   = threadIdx.x + 256 * k;
            const int row = e >> 5;           // 0..63 (point within tile)
            const int c2  = e & 31;           // channel pair
            ushort2 v;
            v.x = f2bf(tile[2 * c2][row]);
            v.y = f2bf(tile[2 * c2 + 1][row]);
            ((ushort2*)(db + (size_t)row * CFEAT))[c2] = v;
        }
    } else {
        const int g = (blockIdx.x - 512) * 256 + threadIdx.x;   // 0..B*N-1
        const int b = g >> 14;
        const int c = cell_of(xyz[g*3], xyz[g*3+1], xyz[g*3+2]);
        atomicAdd(&cnt[b * NCELL + c], 1);
    }
}

// ---------------- scan (redundant per block, in LDS) + scatter ----------------
__global__ __launch_bounds__(256) void prep2_kernel(
    const float* __restrict__ xyz, const int* __restrict__ cnt,
    int* __restrict__ fill, int* __restrict__ cstart,
    float4* __restrict__ pxyzj)
{
    __shared__ int scs[2 * NCELL];       // exclusive starts, both batches
    const int tid  = threadIdx.x;
    const int lane = tid & 63;

    if (tid < 128) {
        const int b = tid >> 6;
        int c16[16];
        int tot = 0;
        #pragma unroll
        for (int k = 0; k < 16; ++k) {
            const int i = lane * 16 + k;
            c16[k] = (i < NCELL) ? cnt[b * NCELL + i] : 0;
            tot += c16[k];
        }
        int ex = tot;
        #pragma unroll
        for (int off = 1; off < 64; off <<= 1) {
            const int u = __shfl_up(ex, off);
            if (lane >= off) ex += u;
        }
        ex -= tot;
        int run = ex;
        #pragma unroll
        for (int k = 0; k < 16; ++k) {
            const int i = lane * 16 + k;
            if (i < NCELL) scs[b * NCELL + i] = run;
            run += c16[k];
        }
    }
    __syncthreads();

    if (blockIdx.x == 0) {
        for (int i = tid; i < 2 * (NCELL + 1); i += 256) {
            const int b  = i / (NCELL + 1);
            const int ci = i - b * (NCELL + 1);
            cstart[i] = (ci == NCELL) ? NPTS : scs[b * NCELL + ci];
        }
    }

    const int g = blockIdx.x * 256 + tid;
    const int b = g >> 14;
    const int j = g & (NPTS - 1);
    const float x = xyz[g*3], y = xyz[g*3+1], z = xyz[g*3+2];
    const int c = cell_of(x, y, z);
    const int pos = atomicAdd(&fill[b * NCELL + c], 1);
    pxyzj[b * NPTS + scs[b * NCELL + c] + pos] =
        make_float4(x, y, z, __int_as_float(j));
}

// ---------------- fused main: ONE WAVE PER QUERY, 4 queries / 256-thr block --
// R10 = R8 exactly (best measured: 109.0 us): XCD-aware swizzle keeps each
// XCD's output writeback contiguous; 2048 blocks preserve full TLP.
// (R9's 4-seq-queries/wave variant cut residency to 2 blocks/CU and
// regressed +12us -> reverted.)
__global__ __launch_bounds__(256) void qg_fused(
    const float* __restrict__ xyz,               // (B, N, 3)
    const float* __restrict__ new_xyz,           // (B, P, 3)
    const int* __restrict__ cstart,              // (B, NCELL+1)
    const float4* __restrict__ pxyzj,            // (B, N) sorted {x,y,z,j}
    const unsigned short* __restrict__ featT16,  // (B, N, C) bf16
    float* __restrict__ out)                     // (B, 67, P, S)
{
    const int tid  = threadIdx.x;       // 0..255
    const int wave = tid >> 6;          // 0..3
    const int lane = tid & 63;
    // XCD swizzle: 2048 blocks, 8 XCDs, bijective. XCD x owns contiguous
    // queries [x*1024, (x+1)*1024) -> contiguous L2 writeback runs.
    const int swz  = ((blockIdx.x & 7) << 8) + (blockIdx.x >> 3);
    const int q    = (swz << 2) + wave;          // 0..B*P-1
    const int b    = q >> 12;
    const int p    = q & (NQ - 1);

    __shared__ __align__(16) unsigned char smem[4 * 2176];
    unsigned char* wbase = smem + wave * 2176;
    unsigned int* hmask  = (unsigned int*)wbase;        // 512 words
    int* idx_s           = (int*)(wbase + 2048);        // 32 ints

    // zero own bitmask: 64 lanes x 2 uint4 = 2KB
    {
        uint4 z; z.x = 0; z.y = 0; z.z = 0; z.w = 0;
        ((uint4*)hmask)[lane * 2]     = z;
        ((uint4*)hmask)[lane * 2 + 1] = z;
    }

    const float qx = new_xyz[q * 3 + 0];
    const float qy = new_xyz[q * 3 + 1];
    const float qz = new_xyz[q * 3 + 2];
    const float* xb = xyz + (size_t)b * NPTS * 3;
    const int* cs = cstart + b * (NCELL + 1);
    const float4* pb = pxyzj + (size_t)b * NPTS;

    int qcx = (int)(qx * GDIM); qcx = qcx < 0 ? 0 : (qcx > GDIM-1 ? GDIM-1 : qcx);
    int qcy = (int)(qy * GDIM); qcy = qcy < 0 ? 0 : (qcy > GDIM-1 ? GDIM-1 : qcy);
    int qcz = (int)(qz * GDIM); qcz = qcz < 0 ? 0 : (qcz > GDIM-1 ? GDIM-1 : qcz);
    const int x0 = qcx > 0 ? qcx - 1 : 0;
    const int x1 = qcx < GDIM-1 ? qcx + 1 : GDIM-1;
    const int y0 = qcy > 0 ? qcy - 1 : 0;
    const int y1 = qcy < GDIM-1 ? qcy + 1 : GDIM-1;
    const int z0 = qcz > 0 ? qcz - 1 : 0;
    const int z1 = qcz < GDIM-1 ? qcz + 1 : GDIM-1;
    const int ny  = y1 - y0 + 1;                 // 2 or 3
    const int nyz = ny * (z1 - z0 + 1);          // up to 9

    int sv = 0, ev = 0;
    if (lane < nyz) {
        const int gzi = (ny == 3) ? ((lane * 86) >> 8) : (lane >> 1);
        const int gyi = lane - gzi * ny;
        const int crow = ((z0 + gzi) * GDIM + (y0 + gyi)) * GDIM;
        sv = cs[crow + x0];
        ev = cs[crow + x1 + 1];
    }
    __builtin_amdgcn_wave_barrier();    // bitmask zero ordered before atomics

    for (int r = 0; r < nyz; ++r) {
        const int s = __shfl(sv, r);
        const int e = __shfl(ev, r);
        for (int pos = s; pos < e; pos += 64) {
            const int i = pos + lane;
            const bool inr = i < e;
            const float4 pt = pb[inr ? i : 0];   // coalesced dwordx4
            const float dx = pt.x - qx;
            const float dy = pt.y - qy;
            const float dz = pt.z - qz;
            if (inr && (dx*dx + dy*dy + dz*dz < R2)) {
                const int j = __float_as_int(pt.w);
                atomicOr(&hmask[j >> 5], 1u << (j & 31));
            }
        }
    }
    __builtin_amdgcn_wave_barrier();    // all hits landed (same-wave DS order)

    // ---- extraction: once per query (one wave) ----
    int K;
    {
        unsigned int w[8];
        const uint4 a = ((const uint4*)hmask)[lane * 2];
        const uint4 c = ((const uint4*)hmask)[lane * 2 + 1];
        w[0] = a.x; w[1] = a.y; w[2] = a.z; w[3] = a.w;
        w[4] = c.x; w[5] = c.y; w[6] = c.z; w[7] = c.w;

        int cnt8 = 0;
        #pragma unroll
        for (int k = 0; k < 8; ++k) cnt8 += __popc(w[k]);

        int pfx = cnt8;
        #pragma unroll
        for (int off = 1; off < 64; off <<= 1) {
            const int u = __shfl_up(pfx, off);
            if (lane >= off) pfx += u;
        }
        K = __shfl(pfx, 63);
        pfx -= cnt8;

        if (pfx < NS && cnt8 > 0) {
            int r = pfx;
            #pragma unroll
            for (int k = 0; k < 8; ++k) {
                unsigned int m = w[k];
                while (m && r < NS) {
                    const int bit = __builtin_ctz(m);
                    idx_s[r] = lane * 256 + k * 32 + bit;
                    m &= m - 1;
                    ++r;
                }
            }
        }
        __builtin_amdgcn_wave_barrier();
        if (lane < NS && lane >= K) {
            idx_s[lane] = (K > 0) ? idx_s[0] : 0;
        }
        __builtin_amdgcn_wave_barrier();
    }

    // ---- gather + direct write (no LDS tile) ----
    const int sm = lane >> 1;           // sample 0..31
    const int h  = lane & 1;            // half-row: 32 channels each
    const int jrow = idx_s[sm];
    const uint4* bptr = (const uint4*)(featT16 +
        ((size_t)b * NPTS + jrow) * CFEAT + (h << 5));
    const uint4 ga = bptr[0];
    const uint4 gb = bptr[1];
    const uint4 gc = bptr[2];
    const uint4 gd = bptr[3];

    const size_t cstride = (size_t)NQ * NS;
    const size_t out_q   = ((size_t)b * COUT * NQ + (size_t)p) * NS;

    if (lane < NS) {
        const int j = idx_s[lane];
        out[out_q + 0*cstride + lane] = xb[j*3+0] - qx;
        out[out_q + 1*cstride + lane] = xb[j*3+1] - qy;
        out[out_q + 2*cstride + lane] = xb[j*3+2] - qz;
    }

    // lane (sm,h) holds 32 channels (16 dwords) of sample sm.
    float* fob = out + out_q + (size_t)(3 + (h << 5)) * cstride + sm;
    const unsigned comps[16] = {ga.x, ga.y, ga.z, ga.w,
                                gb.x, gb.y, gb.z, gb.w,
                                gc.x, gc.y, gc.z, gc.w,
                                gd.x, gd.y, gd.z, gd.w};
    #pragma unroll
    for (int kk = 0; kk < 16; ++kk) {
        const unsigned u = comps[kk];
        fob[(size_t)(2*kk)     * cstride] = __uint_as_float(u << 16);          // even ch
        fob[(size_t)(2*kk + 1) * cstride] = __uint_as_float(u & 0xFFFF0000u);  // odd ch
    }
}

// ---------------- fallback: linear-scan kernel (fp32 exact) ----------------
__global__ __launch_bounds__(256) void qg_linear(
    const float* __restrict__ xyz, const float* __restrict__ new_xyz,
    const float* __restrict__ feat, float* __restrict__ out)
{
    const int wave = threadIdx.x >> 6;
    const int lane = threadIdx.x & 63;
    const int bp   = blockIdx.x * 4 + wave;
    const int b    = bp >> 12;
    const int p    = bp & (NQ - 1);
    __shared__ int idx_s[4][NS];
    const float qx = new_xyz[bp*3+0], qy = new_xyz[bp*3+1], qz = new_xyz[bp*3+2];
    const float* xb = xyz + (size_t)b * NPTS * 3;
    int cnt = 0;
    const unsigned long long below = (1ull << lane) - 1ull;
    for (int base = 0; base < NPTS; base += 64) {
        const int j = base + lane;
        const float dx = xb[j*3+0]-qx, dy = xb[j*3+1]-qy, dz = xb[j*3+2]-qz;
        const bool hit = dx*dx+dy*dy+dz*dz < R2;
        const unsigned long long m = __ballot(hit);
        if (hit) {
            const int slot = cnt + __popcll(m & below);
            if (slot < NS) idx_s[wave][slot] = j;
        }
        cnt += __popcll(m);
        if (cnt >= NS) break;
    }
    __builtin_amdgcn_wave_barrier();
    if (cnt < NS) {
        const int first = (cnt > 0) ? idx_s[wave][0] : 0;
        if (lane >= cnt && lane < NS) idx_s[wave][lane] = first;
    }
    __builtin_amdgcn_wave_barrier();
    const size_t cstride = (size_t)NQ * NS;
    const size_t out_q = ((size_t)b * COUT * NQ + (size_t)p) * NS;
    if (lane < NS) {
        const int j = idx_s[wave][lane];
        out[out_q + 0*cstride + lane] = xb[j*3+0] - qx;
        out[out_q + 1*cstride + lane] = xb[j*3+1] - qy;
        out[out_q + 2*cstride + lane] = xb[j*3+2] - qz;
    }
    const float* fb = feat + (size_t)b * CFEAT * NPTS;
    const int s = lane & 31, half = lane >> 5;
    const int j = idx_s[wave][s];
    #pragma unroll 8
    for (int c = half; c < CFEAT; c += 2)
        out[out_q + (size_t)(3 + c) * cstride + s] = fb[(size_t)c * NPTS + j];
}

extern "C" void kernel_launch(void* const* d_in, const int* in_sizes, int n_in,
                              void* d_out, int out_size, void* d_ws, size_t ws_size,
                              hipStream_t stream) {
    const float* xyz     = (const float*)d_in[0];  // (2,16384,3)
    const float* new_xyz = (const float*)d_in[1];  // (2,4096,3)
    const float* feat    = (const float*)d_in[2];  // (2,64,16384)
    float* out = (float*)d_out;                    // (2,67,4096,32)

    const size_t need_full = FEATT_BYTES + PXYZJ_BYTES + (size_t)GRID_INTS * sizeof(int);

    if (ws_size >= need_full) {
        unsigned short* featT16 = (unsigned short*)d_ws;
        float4* pxyzj = (float4*)((char*)d_ws + FEATT_BYTES);
        int* gi = (int*)((char*)d_ws + FEATT_BYTES + PXYZJ_BYTES);
        int* cnt    = gi + OFF_CNT;
        int* fill   = gi + OFF_FILL;
        int* cstart = gi + OFF_CSTART;

        hipMemsetAsync(cnt, 0, 4 * NCELL * sizeof(int), stream);  // cnt + fill
        prep1_kernel<<<512 + (BATCH * NPTS) / 256, 256, 0, stream>>>(feat, featT16, xyz, cnt);
        prep2_kernel<<<(BATCH * NPTS) / 256, 256, 0, stream>>>(xyz, cnt, fill, cstart, pxyzj);
        qg_fused<<<(BATCH * NQ) / 4, 256, 0, stream>>>(
            xyz, new_xyz, cstart, pxyzj, featT16, out);
    } else {
        qg_linear<<<(BATCH * NQ) / 4, 256, 0, stream>>>(xyz, new_xyz, feat, out);
    }
}